// Round 7
// baseline (37.784 us; speedup 1.0000x reference)
//
#include <hip/hip_runtime.h>

#define COLS    65536
#define ROWS    512
#define K_RANK  58981u          /* floor(0.9*(COLS-1)); frac = 0.5 */
#define PARTS   4
#define SEG     (COLS / PARTS)  /* 16384 floats = 64 KB */
#define T1      256
#define T2      256
#define SLOTS   12u
#define SSTRIDE 13
#define CAPSEG  768             /* expected ~333/part, +24 sigma margin */
#define LO_F    1.23f
#define HI_F    1.34f
#define BIGF    3.0e38f

/* ws layout (32-bit indices):
   u[0    + rp] nSeg      u[2048 + rp] ovf       u[4096 + rp] cntLow
   u[6144 + rp] cntHigh   f[8192 + rp] sumHigh   f[10240+ rp] minHigh
   f[16384 + rp*CAPSEG ...] cap segments (2048*768*4B = 6.3 MB)
   rp = row*PARTS + part. All slots owner-written -> no pre-zeroing. */
#define NSEG_U   0
#define OVF_U    2048
#define CLOW_U   4096
#define CHIGH_U  6144
#define SHIGH_F  8192
#define MINH_F   10240
#define CAP_F    16384

__device__ __forceinline__ unsigned key_of(float x) {
    unsigned b = __float_as_uint(x);
    return (b & 0x80000000u) ? ~b : (b | 0x80000000u);
}
__device__ __forceinline__ float float_of_key(unsigned u) {
    unsigned b = (u & 0x80000000u) ? (u & 0x7FFFFFFFu) : ~u;
    return __uint_as_float(b);
}
__device__ __forceinline__ float wredF(float v) {
    #pragma unroll
    for (int o = 32; o > 0; o >>= 1) v += __shfl_down(v, o);
    return v;
}
__device__ __forceinline__ unsigned wredU(unsigned v) {
    #pragma unroll
    for (int o = 32; o > 0; o >>= 1) v += __shfl_down(v, o);
    return v;
}
__device__ __forceinline__ unsigned wredMinU(unsigned v) {
    #pragma unroll
    for (int o = 32; o > 0; o >>= 1) { unsigned n = __shfl_down(v, o); v = (n < v) ? n : v; }
    return v;
}
__device__ __forceinline__ float wredMinF(float v) {
    #pragma unroll
    for (int o = 32; o > 0; o >>= 1) v = fminf(v, __shfl_down(v, o));
    return v;
}

/* ================= K1: stream + deterministic capture ================= */
__global__ __launch_bounds__(T1, 8)     /* 8 waves/EU -> 32 waves/CU, VGPR<=64 */
void k1_stream(const float* __restrict__ X, unsigned* __restrict__ wsu,
               float* __restrict__ wsf) {
    const int bid  = blockIdx.x;
    const int row  = bid >> 2;
    const int part = bid & 3;
    const int rp   = row * PARTS + part;
    const int tid  = threadIdx.x;
    const int lane = tid & 63;
    const int wid  = tid >> 6;
    const float4* x4 = (const float4*)(X + (size_t)row * COLS + (size_t)part * SEG);

    __shared__ float    slot[T1 * SSTRIDE];   /* 13312 B */
    __shared__ unsigned wTot[4], ovfW[4], rU1[4], rU2[4];
    __shared__ float    rF1[4], rF2[4];

    float* ms = &slot[tid * SSTRIDE];
    unsigned cnt = 0u, cLow = 0u, cHigh = 0u;
    float    sHigh = 0.f, mHigh = BIGF;

#define PROC(xx) { float x_ = (xx); \
    if (x_ < LO_F) { cLow += 1u; } \
    else if (x_ >= HI_F) { sHigh += x_; cHigh += 1u; mHigh = fminf(mHigh, x_); } \
    else { if (cnt < SLOTS) ms[cnt] = x_; cnt += 1u; } }

    #pragma unroll 8
    for (int k = 0; k < SEG / 4 / T1; ++k) {      /* 16 iters */
        float4 v = x4[tid + k * T1];
        PROC(v.x) PROC(v.y) PROC(v.z) PROC(v.w)
    }
#undef PROC

    /* deterministic block-local placement: wave prefix + wave totals */
    const unsigned myN = (cnt < SLOTS) ? cnt : SLOTS;
    unsigned pre = myN;
    #pragma unroll
    for (int o = 1; o < 64; o <<= 1) { unsigned n = __shfl_up(pre, o); if (lane >= o) pre += n; }
    const unsigned excl = pre - myN;
    unsigned long long ovfm = __ballot(cnt > SLOTS);
    {
        unsigned a = wredU(cLow), b = wredU(cHigh);
        float    s = wredF(sHigh), m = wredMinF(mHigh);
        if (lane == 63) wTot[wid] = pre;
        if (lane == 0) { ovfW[wid] = (ovfm != 0ull) ? 1u : 0u;
                         rU1[wid] = a; rU2[wid] = b; rF1[wid] = s; rF2[wid] = m; }
    }
    __syncthreads();
    unsigned base = 0u;
    for (int w = 0; w < 4; ++w) if (w < wid) base += wTot[w];
    float* seg = wsf + CAP_F + (size_t)rp * CAPSEG;
    const unsigned p = base + excl;
    for (unsigned j = 0; j < myN; ++j)
        if (p + j < (unsigned)CAPSEG) seg[p + j] = ms[j];

    if (tid == 0) {
        unsigned tot = wTot[0] + wTot[1] + wTot[2] + wTot[3];
        unsigned ov  = ovfW[0] | ovfW[1] | ovfW[2] | ovfW[3] | (tot > (unsigned)CAPSEG ? 1u : 0u);
        wsu[NSEG_U  + rp] = tot;
        wsu[OVF_U   + rp] = ov;
        wsu[CLOW_U  + rp] = rU1[0] + rU1[1] + rU1[2] + rU1[3];
        wsu[CHIGH_U + rp] = rU2[0] + rU2[1] + rU2[2] + rU2[3];
        wsf[SHIGH_F + rp] = rF1[0] + rF1[1] + rF1[2] + rF1[3];
        wsf[MINH_F  + rp] = fminf(fminf(rF2[0], rF2[1]), fminf(rF2[2], rF2[3]));
    }
}

/* ================= K2: exact select + mean ================= */
__global__ __launch_bounds__(T2)
void k2_select(const float* __restrict__ X, const unsigned* __restrict__ wsu,
               const float* __restrict__ wsf, float* __restrict__ out) {
    const int row  = blockIdx.x;
    const int tid  = threadIdx.x;
    const int lane = tid & 63;
    const int wid  = tid >> 6;

    __shared__ float    cap[PARTS * CAPSEG];   /* 12288 B */
    __shared__ float    cand[128];
    __shared__ unsigned hist[64];
    __shared__ unsigned rU1[4], rU2[4];
    __shared__ float    rF1[4];
    __shared__ unsigned nOff[PARTS + 1];
    __shared__ unsigned cntLowSh, cHighSh, nCand, rSh;
    __shared__ float    sHighSh, minHighSh, vrSh, tSh;
    __shared__ int      fail, selBin, fBin;
    __shared__ unsigned selBase, fBase;
    __shared__ unsigned loS, hiS;

    if (tid == 0) {
        unsigned cl = 0u, ch = 0u, ov = 0u, off = 0u;
        float sh = 0.f, mh = BIGF;
        for (int pt = 0; pt < PARTS; ++pt) {
            int rp = row * PARTS + pt;
            nOff[pt] = off;
            unsigned n = wsu[NSEG_U + rp];
            off += n;
            ov |= wsu[OVF_U + rp];
            cl += wsu[CLOW_U + rp];
            ch += wsu[CHIGH_U + rp];
            sh += wsf[SHIGH_F + rp];
            mh  = fminf(mh, wsf[MINH_F + rp]);
        }
        nOff[PARTS] = off;
        cntLowSh = cl; cHighSh = ch; sHighSh = sh; minHighSh = mh;
        fail = (ov != 0u) || (cl > K_RANK) || (cl + off < K_RANK + 2u);
        rSh = K_RANK - cl;
        nCand = 0u;
    }
    __syncthreads();

    const unsigned LOBITS = __float_as_uint(LO_F);
    const unsigned capN = nOff[PARTS];

    if (!fail) {
        /* gather segments into contiguous LDS (deterministic order) */
        for (int pt = 0; pt < PARTS; ++pt) {
            const float* seg = wsf + CAP_F + (size_t)(row * PARTS + pt) * CAPSEG;
            const unsigned o = nOff[pt], n = nOff[pt + 1] - o;
            for (unsigned i = tid; i < n; i += T2) cap[o + i] = seg[i];
        }
        if (tid < 64) hist[tid] = 0u;
        __syncthreads();
        for (unsigned i = tid; i < capN; i += T2) {
            unsigned d = __float_as_uint(cap[i]) - LOBITS;
            atomicAdd(&hist[d >> 16], 1u);
        }
        __syncthreads();
        const unsigned r = rSh;
        if (wid == 0) {
            unsigned v = hist[lane], incl = v;
            #pragma unroll
            for (int o = 1; o < 64; o <<= 1) { unsigned n = __shfl_up(incl, o); if (lane >= o) incl += n; }
            unsigned excl = incl - v;
            if (v && excl <= r && r < incl) { selBin = lane; selBase = excl; }
        }
        __syncthreads();
        const int B = selBin;
        const unsigned j1 = r - selBase;
        if (tid < 64) hist[tid] = 0u;
        __syncthreads();
        for (unsigned i = tid; i < capN; i += T2) {
            unsigned d = __float_as_uint(cap[i]) - LOBITS;
            if ((int)(d >> 16) == B) atomicAdd(&hist[(d >> 10) & 63u], 1u);
        }
        __syncthreads();
        if (wid == 0) {
            unsigned v = hist[lane], incl = v;
            #pragma unroll
            for (int o = 1; o < 64; o <<= 1) { unsigned n = __shfl_up(incl, o); if (lane >= o) incl += n; }
            unsigned excl = incl - v;
            if (v && excl <= j1 && j1 < incl) { fBin = lane; fBase = excl; }
        }
        __syncthreads();
        const int F = fBin;
        const unsigned j2 = j1 - fBase;
        for (unsigned i = tid; i < capN; i += T2) {
            unsigned d = __float_as_uint(cap[i]) - LOBITS;
            if ((int)(d >> 16) == B && (int)((d >> 10) & 63u) == F) {
                unsigned idx = atomicAdd(&nCand, 1u);
                if (idx < 128u) cand[idx] = cap[i];
            }
        }
        __syncthreads();
        if (tid == 0 && nCand > 128u) fail = 1;
        __syncthreads();
        if (!fail) {
            unsigned nC = nCand;
            if (tid < (int)nC) {
                float v = cand[tid];
                unsigned lt = 0u, eq = 0u;
                for (unsigned i = 0; i < nC; ++i) {
                    float c = cand[i];
                    lt += (c < v) ? 1u : 0u;
                    eq += (c == v) ? 1u : 0u;
                }
                if (lt <= j2 && j2 < lt + eq) vrSh = v;
            }
        }
        __syncthreads();
        if (!fail) {
            const float vr = vrSh;
            unsigned le = 0u; float m1 = BIGF;
            for (unsigned i = tid; i < capN; i += T2) {
                float x = cap[i];
                le += (x <= vr) ? 1u : 0u;
                if (x > vr) m1 = fminf(m1, x);
            }
            le = wredU(le); m1 = wredMinF(m1);
            if (lane == 0) { rU1[wid] = le; rF1[wid] = m1; }
            __syncthreads();
            if (tid == 0) {
                unsigned LE = cntLowSh; float M1 = minHighSh;
                for (int w = 0; w < 4; ++w) { LE += rU1[w]; M1 = fminf(M1, rF1[w]); }
                float vr0 = vrSh;
                float v1  = (LE >= K_RANK + 2u) ? vr0 : M1;   /* tie-run -> s[K+1]==s[K] */
                if (v1 >= BIGF) fail = 1;
                float t = vr0 + 0.5f * (v1 - vr0);
                if (cHighSh > 0u && t >= minHighSh) fail = 1; /* midpoint reached high region */
                tSh = t;
            }
            __syncthreads();
        }
    }
    __syncthreads();

    if (!fail) {
        const float t = tSh;
        float s = 0.f; unsigned c = 0u;
        for (unsigned i = tid; i < capN; i += T2) {
            float x = cap[i];
            if (x > t) { s += x; c += 1u; }
        }
        s = wredF(s); c = wredU(c);
        if (lane == 0) { rF1[wid] = s; rU1[wid] = c; }
        __syncthreads();
        if (tid == 0) {
            float S = sHighSh; unsigned C = cHighSh;
            for (int w = 0; w < 4; ++w) { S += rF1[w]; C += rU1[w]; }
            out[row] = S / (float)((C > 0u) ? C : 1u);
        }
    } else {
        /* fallback: exact bisection on monotone keys (full re-read of the row) */
        const float4* x4 = (const float4*)(X + (size_t)row * COLS);
        if (tid == 0) { loS = 0u; hiS = 0xFFFFFFFFu; }
        __syncthreads();
        for (int it = 0; it < 32; ++it) {
            unsigned mid = loS + ((hiS - loS) >> 1);
            unsigned c = 0u;
            for (int i = tid; i < COLS / 4; i += T2) {
                float4 v = x4[i];
                c += (key_of(v.x) <= mid) ? 1u : 0u;
                c += (key_of(v.y) <= mid) ? 1u : 0u;
                c += (key_of(v.z) <= mid) ? 1u : 0u;
                c += (key_of(v.w) <= mid) ? 1u : 0u;
            }
            c = wredU(c);
            if (lane == 0) rU1[wid] = c;
            __syncthreads();
            if (tid == 0) {
                unsigned t = rU1[0] + rU1[1] + rU1[2] + rU1[3];
                if (t >= K_RANK + 1u) hiS = mid; else loS = mid + 1u;
            }
            __syncthreads();
        }
        {
            const unsigned kap = loS;
            unsigned c = 0u, mA = 0xFFFFFFFFu;
            for (int i = tid; i < COLS / 4; i += T2) {
                float4 v = x4[i];
                float vv[4] = { v.x, v.y, v.z, v.w };
                #pragma unroll
                for (int cc = 0; cc < 4; ++cc) {
                    unsigned u = key_of(vv[cc]);
                    if (u <= kap) c += 1u; else mA = (u < mA) ? u : mA;
                }
            }
            c = wredU(c); mA = wredMinU(mA);
            if (lane == 0) { rU1[wid] = c; rU2[wid] = mA; }
            __syncthreads();
            if (tid == 0) {
                unsigned tot = rU1[0] + rU1[1] + rU1[2] + rU1[3];
                unsigned m = rU2[0];
                for (int w = 1; w < 4; ++w) m = (rU2[w] < m) ? rU2[w] : m;
                float vk  = float_of_key(kap);
                float vk1 = (tot >= K_RANK + 2u) ? vk : float_of_key(m);
                tSh = vk + 0.5f * (vk1 - vk);
            }
            __syncthreads();
        }
        {
            const float t = tSh;
            float s = 0.f; unsigned c = 0u;
            for (int i = tid; i < COLS / 4; i += T2) {
                float4 v = x4[i];
                if (v.x > t) { s += v.x; c += 1u; }
                if (v.y > t) { s += v.y; c += 1u; }
                if (v.z > t) { s += v.z; c += 1u; }
                if (v.w > t) { s += v.w; c += 1u; }
            }
            s = wredF(s); c = wredU(c);
            if (lane == 0) { rF1[wid] = s; rU1[wid] = c; }
            __syncthreads();
            if (tid == 0) {
                float S = 0.f; unsigned C = 0u;
                for (int w = 0; w < 4; ++w) { S += rF1[w]; C += rU1[w]; }
                out[row] = S / (float)((C > 0u) ? C : 1u);
            }
        }
    }
}

extern "C" void kernel_launch(void* const* d_in, const int* in_sizes, int n_in,
                              void* d_out, int out_size, void* d_ws, size_t ws_size,
                              hipStream_t stream) {
    const float* X = (const float*)d_in[0];
    float* out = (float*)d_out;
    unsigned* wsu = (unsigned*)d_ws;
    float*    wsf = (float*)d_ws;
    const int rows = in_sizes[0] / COLS;   /* 512 */
    k1_stream<<<rows * PARTS, T1, 0, stream>>>(X, wsu, wsf);
    k2_select<<<rows, T2, 0, stream>>>(X, wsu, wsf, out);
}

// Round 8
// 31.870 us; speedup vs baseline: 1.1856x; 1.1856x over previous
//
#include <hip/hip_runtime.h>

#define COLS    65536
#define THREADS 512
#define K_RANK  58981u          /* floor(0.9*(COLS-1)); frac = 0.5 */
#define SLOTS   12u
#define SSTRIDE 13              /* 12 data slots + 1 sacrificial; gcd(13,32)=1 */
#define LO_F    1.25f
#define HI_F    1.325f
#define BIGF    3.0e38f
#define EPT     (COLS / THREADS)   /* 128 elements per thread */

__device__ __forceinline__ unsigned key_of(float x) {
    unsigned b = __float_as_uint(x);
    return (b & 0x80000000u) ? ~b : (b | 0x80000000u);
}
__device__ __forceinline__ float float_of_key(unsigned u) {
    unsigned b = (u & 0x80000000u) ? (u & 0x7FFFFFFFu) : ~u;
    return __uint_as_float(b);
}
__device__ __forceinline__ float wredF(float v) {
    #pragma unroll
    for (int o = 32; o > 0; o >>= 1) v += __shfl_down(v, o);
    return v;
}
__device__ __forceinline__ unsigned wredU(unsigned v) {
    #pragma unroll
    for (int o = 32; o > 0; o >>= 1) v += __shfl_down(v, o);
    return v;
}
__device__ __forceinline__ unsigned wredMaxU(unsigned v) {
    #pragma unroll
    for (int o = 32; o > 0; o >>= 1) { unsigned n = __shfl_down(v, o); v = (n > v) ? n : v; }
    return v;
}
__device__ __forceinline__ unsigned wredMinU(unsigned v) {
    #pragma unroll
    for (int o = 32; o > 0; o >>= 1) { unsigned n = __shfl_down(v, o); v = (n < v) ? n : v; }
    return v;
}
__device__ __forceinline__ float wredMinF(float v) {
    #pragma unroll
    for (int o = 32; o > 0; o >>= 1) v = fminf(v, __shfl_down(v, o));
    return v;
}

__global__ __launch_bounds__(THREADS, 4)   /* VGPR<=128 -> 2 blocks/CU */
void dtp_kernel(const float* __restrict__ X, float* __restrict__ out) {
    /* XCD-bijective row swizzle: 512 = 8 XCD * 64 */
    const int bid  = blockIdx.x;
    const int row  = (bid & 7) * 64 + (bid >> 3);
    const int tid  = threadIdx.x;
    const int lane = tid & 63;
    const int wid  = tid >> 6;
    const float4* x4 = (const float4*)(X + (size_t)row * COLS);

    __shared__ float    slot[THREADS * SSTRIDE];   /* 26624 B */
    __shared__ float    cand[128];
    __shared__ unsigned hist[64];
    __shared__ unsigned rU1[8], rU2[8], rU3[8];
    __shared__ float    rF1[8];
    __shared__ unsigned cntLowSh, cHighSh, nCand, rSh;
    __shared__ float    sHighSh, vrSh, tSh;
    __shared__ int      fail, selBin, fBin;
    __shared__ unsigned selBase, fBase;
    __shared__ unsigned loS, hiS;

    if (tid == 0) { fail = 0; nCand = 0u; }
    __syncthreads();

    const unsigned LOBITS = __float_as_uint(LO_F);
    const unsigned WRANGE = __float_as_uint(HI_F) - LOBITS;
    float* ms = &slot[tid * SSTRIDE];

    /* ---------- phase 1: branch-free stream, 32 B/lane (2x float4) ---------- */
    unsigned cntT = 0u, cHigh = 0u;
    float    sHigh = 0.f;

#define PROC(xx) { float x_ = (xx); \
    unsigned d_ = __float_as_uint(x_) - LOBITS; \
    cHigh += (x_ >= HI_F) ? 1u : 0u; \
    sHigh += (x_ >= HI_F) ? x_ : 0.f; \
    ms[(cntT < SLOTS) ? cntT : SLOTS] = x_; \
    cntT  += (d_ < WRANGE) ? 1u : 0u; }

    #pragma unroll 4
    for (int k = 0; k < COLS / 8 / THREADS; ++k) {       /* 16 iters, 2 float4 each */
        const int b = 2 * (tid + k * THREADS);
        float4 v0 = x4[b];
        float4 v1 = x4[b + 1];
        PROC(v0.x) PROC(v0.y) PROC(v0.z) PROC(v0.w)
        PROC(v1.x) PROC(v1.y) PROC(v1.z) PROC(v1.w)
    }
#undef PROC

    const unsigned myN  = (cntT < SLOTS) ? cntT : SLOTS;
    const unsigned cLow = (unsigned)EPT - cntT - cHigh;
    {
        unsigned a = wredU(cLow), b = wredU(cntT), mx = wredMaxU(cntT);
        float    s = wredF(sHigh);
        if (lane == 0) { rU1[wid] = a; rU2[wid] = b; rU3[wid] = mx; rF1[wid] = s; }
    }
    __syncthreads();
    if (tid == 0) {
        unsigned CL = 0u, CT = 0u, MX = 0u; float SH = 0.f;
        for (int w = 0; w < 8; ++w) {
            CL += rU1[w]; CT += rU2[w]; MX = (rU3[w] > MX) ? rU3[w] : MX;
            SH += rF1[w];
        }
        cntLowSh = CL; cHighSh = (unsigned)COLS - CL - CT; sHighSh = SH;
        if (MX > SLOTS || CL > K_RANK || CL + CT < K_RANK + 2u) fail = 1;
        rSh = K_RANK - CL;
    }
    __syncthreads();

    /* ---------- phase 2: exact select of rank r among captured ---------- */
    if (!fail) {
        if (tid < 64) hist[tid] = 0u;
        __syncthreads();
        for (unsigned j = 0; j < myN; ++j) {
            unsigned d = __float_as_uint(ms[j]) - LOBITS;
            atomicAdd(&hist[d >> 16], 1u);
        }
        __syncthreads();
        const unsigned r = rSh;
        if (wid == 0) {
            unsigned v = hist[lane], incl = v;
            #pragma unroll
            for (int o = 1; o < 64; o <<= 1) { unsigned n = __shfl_up(incl, o); if (lane >= o) incl += n; }
            unsigned excl = incl - v;
            if (v && excl <= r && r < incl) { selBin = lane; selBase = excl; }
        }
        __syncthreads();
        const int B = selBin;
        const unsigned j1 = r - selBase;
        if (tid < 64) hist[tid] = 0u;
        __syncthreads();
        for (unsigned j = 0; j < myN; ++j) {
            unsigned d = __float_as_uint(ms[j]) - LOBITS;
            if ((int)(d >> 16) == B) atomicAdd(&hist[(d >> 10) & 63u], 1u);
        }
        __syncthreads();
        if (wid == 0) {
            unsigned v = hist[lane], incl = v;
            #pragma unroll
            for (int o = 1; o < 64; o <<= 1) { unsigned n = __shfl_up(incl, o); if (lane >= o) incl += n; }
            unsigned excl = incl - v;
            if (v && excl <= j1 && j1 < incl) { fBin = lane; fBase = excl; }
        }
        __syncthreads();
        const int F = fBin;
        const unsigned j2 = j1 - fBase;
        for (unsigned j = 0; j < myN; ++j) {
            unsigned d = __float_as_uint(ms[j]) - LOBITS;
            if ((int)(d >> 16) == B && (int)((d >> 10) & 63u) == F) {
                unsigned idx = atomicAdd(&nCand, 1u);
                if (idx < 128u) cand[idx] = ms[j];
            }
        }
        __syncthreads();
        if (tid == 0 && nCand > 128u) fail = 1;
        __syncthreads();
        if (!fail) {
            unsigned nC = nCand;
            if (tid < (int)nC) {
                float v = cand[tid];
                unsigned lt = 0u, eq = 0u;
                for (unsigned i = 0; i < nC; ++i) {
                    float c = cand[i];
                    lt += (c < v) ? 1u : 0u;
                    eq += (c == v) ? 1u : 0u;
                }
                if (lt <= j2 && j2 < lt + eq) vrSh = v;
            }
        }
        __syncthreads();
        if (!fail) {
            /* s[K+1]: count <=vr (tie-run test) and min of capture above vr */
            const float vr = vrSh;
            unsigned le = 0u; float m1 = BIGF;
            for (unsigned j = 0; j < myN; ++j) {
                float x = ms[j];
                le += (x <= vr) ? 1u : 0u;
                if (x > vr) m1 = fminf(m1, x);
            }
            le = wredU(le); m1 = wredMinF(m1);
            if (lane == 0) { rU1[wid] = le; rF1[wid] = m1; }
            __syncthreads();
            if (tid == 0) {
                unsigned LE = cntLowSh; float M1 = BIGF;
                for (int w = 0; w < 8; ++w) { LE += rU1[w]; M1 = fminf(M1, rF1[w]); }
                float vr0 = vrSh;
                float v1  = (LE >= K_RANK + 2u) ? vr0 : M1;   /* tie-run -> s[K+1]==s[K] */
                if (v1 >= BIGF) fail = 1;                     /* s[K+1] not in window -> fallback */
                tSh = vr0 + 0.5f * (v1 - vr0);                /* t < HI <= every high value */
            }
            __syncthreads();
        }
    }
    __syncthreads();

    if (!fail) {
        /* ---------- phase 3: mean over {x > t} = window-part + high-part ---------- */
        const float t = tSh;
        float s = 0.f; unsigned c = 0u;
        for (unsigned j = 0; j < myN; ++j) {
            float x = ms[j];
            if (x > t) { s += x; c += 1u; }
        }
        s = wredF(s); c = wredU(c);
        if (lane == 0) { rF1[wid] = s; rU1[wid] = c; }
        __syncthreads();
        if (tid == 0) {
            float S = sHighSh; unsigned C = cHighSh;
            for (int w = 0; w < 8; ++w) { S += rF1[w]; C += rU1[w]; }
            out[row] = S / (float)((C > 0u) ? C : 1u);
        }
    } else {
        /* ---------- fallback: exact bisection on monotone keys (full re-read) ---------- */
        if (tid == 0) { loS = 0u; hiS = 0xFFFFFFFFu; }
        __syncthreads();
        for (int it = 0; it < 32; ++it) {
            unsigned mid = loS + ((hiS - loS) >> 1);
            unsigned c = 0u;
            for (int i = tid; i < COLS / 4; i += THREADS) {
                float4 v = x4[i];
                c += (key_of(v.x) <= mid) ? 1u : 0u;
                c += (key_of(v.y) <= mid) ? 1u : 0u;
                c += (key_of(v.z) <= mid) ? 1u : 0u;
                c += (key_of(v.w) <= mid) ? 1u : 0u;
            }
            c = wredU(c);
            if (lane == 0) rU1[wid] = c;
            __syncthreads();
            if (tid == 0) {
                unsigned t = 0u;
                for (int w = 0; w < 8; ++w) t += rU1[w];
                if (t >= K_RANK + 1u) hiS = mid; else loS = mid + 1u;
            }
            __syncthreads();
        }
        {
            const unsigned kap = loS;
            unsigned c = 0u, mA = 0xFFFFFFFFu;
            for (int i = tid; i < COLS / 4; i += THREADS) {
                float4 v = x4[i];
                float vv[4] = { v.x, v.y, v.z, v.w };
                #pragma unroll
                for (int cc = 0; cc < 4; ++cc) {
                    unsigned u = key_of(vv[cc]);
                    if (u <= kap) c += 1u; else mA = (u < mA) ? u : mA;
                }
            }
            c = wredU(c); mA = wredMinU(mA);
            if (lane == 0) { rU1[wid] = c; rU2[wid] = mA; }
            __syncthreads();
            if (tid == 0) {
                unsigned tot = 0u, m = 0xFFFFFFFFu;
                for (int w = 0; w < 8; ++w) { tot += rU1[w]; m = (rU2[w] < m) ? rU2[w] : m; }
                float vk  = float_of_key(kap);
                float vk1 = (tot >= K_RANK + 2u) ? vk : float_of_key(m);
                tSh = vk + 0.5f * (vk1 - vk);
            }
            __syncthreads();
        }
        {
            const float t = tSh;
            float s = 0.f; unsigned c = 0u;
            for (int i = tid; i < COLS / 4; i += THREADS) {
                float4 v = x4[i];
                if (v.x > t) { s += v.x; c += 1u; }
                if (v.y > t) { s += v.y; c += 1u; }
                if (v.z > t) { s += v.z; c += 1u; }
                if (v.w > t) { s += v.w; c += 1u; }
            }
            s = wredF(s); c = wredU(c);
            if (lane == 0) { rF1[wid] = s; rU1[wid] = c; }
            __syncthreads();
            if (tid == 0) {
                float S = 0.f; unsigned C = 0u;
                for (int w = 0; w < 8; ++w) { S += rF1[w]; C += rU1[w]; }
                out[row] = S / (float)((C > 0u) ? C : 1u);
            }
        }
    }
}

extern "C" void kernel_launch(void* const* d_in, const int* in_sizes, int n_in,
                              void* d_out, int out_size, void* d_ws, size_t ws_size,
                              hipStream_t stream) {
    const float* X = (const float*)d_in[0];
    float* out = (float*)d_out;
    const int rows = in_sizes[0] / COLS;   /* 512 */
    dtp_kernel<<<rows, THREADS, 0, stream>>>(X, out);
}

// Round 9
// 31.603 us; speedup vs baseline: 1.1956x; 1.0084x over previous
//
#include <hip/hip_runtime.h>

#define COLS    65536
#define THREADS 512
#define K_RANK  58981u          /* floor(0.9*(COLS-1)); frac = 0.5 */
#define SLOTS   12u
#define SSTRIDE 13              /* 12 data slots + 1 sacrificial; gcd(13,32)=1 */
#define LO_F    1.25f
#define HI_F    1.325f
#define BIGF    3.0e38f
#define EPT     (COLS / THREADS)   /* 128 elements per thread */

__device__ __forceinline__ unsigned key_of(float x) {
    unsigned b = __float_as_uint(x);
    return (b & 0x80000000u) ? ~b : (b | 0x80000000u);
}
__device__ __forceinline__ float float_of_key(unsigned u) {
    unsigned b = (u & 0x80000000u) ? (u & 0x7FFFFFFFu) : ~u;
    return __uint_as_float(b);
}
__device__ __forceinline__ float wredF(float v) {
    #pragma unroll
    for (int o = 32; o > 0; o >>= 1) v += __shfl_down(v, o);
    return v;
}
__device__ __forceinline__ unsigned wredU(unsigned v) {
    #pragma unroll
    for (int o = 32; o > 0; o >>= 1) v += __shfl_down(v, o);
    return v;
}
__device__ __forceinline__ unsigned wredMaxU(unsigned v) {
    #pragma unroll
    for (int o = 32; o > 0; o >>= 1) { unsigned n = __shfl_down(v, o); v = (n > v) ? n : v; }
    return v;
}
__device__ __forceinline__ unsigned wredMinU(unsigned v) {
    #pragma unroll
    for (int o = 32; o > 0; o >>= 1) { unsigned n = __shfl_down(v, o); v = (n < v) ? n : v; }
    return v;
}
__device__ __forceinline__ float wredMinF(float v) {
    #pragma unroll
    for (int o = 32; o > 0; o >>= 1) v = fminf(v, __shfl_down(v, o));
    return v;
}

__global__ __launch_bounds__(THREADS, 4)   /* VGPR<=128 -> 2 blocks/CU */
void dtp_kernel(const float* __restrict__ X, float* __restrict__ out) {
    /* XCD-bijective row swizzle: 512 = 8 XCD * 64 */
    const int bid  = blockIdx.x;
    const int row  = (bid & 7) * 64 + (bid >> 3);
    const int tid  = threadIdx.x;
    const int lane = tid & 63;
    const int wid  = tid >> 6;
    const float4* x4 = (const float4*)(X + (size_t)row * COLS);

    __shared__ float    slot[THREADS * SSTRIDE];   /* 26624 B */
    __shared__ float    cand[128];
    __shared__ unsigned hist[64];
    __shared__ unsigned rU1[8], rU2[8], rU3[8];
    __shared__ float    rF1[8];
    __shared__ unsigned cntLowSh, cHighSh, nCand, rSh;
    __shared__ float    sHighSh, vrSh, tSh;
    __shared__ int      fail, selBin, fBin;
    __shared__ unsigned selBase, fBase;
    __shared__ unsigned loS, hiS;

    if (tid == 0) { fail = 0; nCand = 0u; }
    __syncthreads();

    const unsigned LOBITS = __float_as_uint(LO_F);
    const unsigned WRANGE = __float_as_uint(HI_F) - LOBITS;
    float* ms = &slot[tid * SSTRIDE];

    /* ---------- phase 1: branch-free stream, 64 B/lane (4x float4) ---------- */
    unsigned cntT = 0u, cHigh = 0u;
    float    sHigh = 0.f;

#define PROC(xx) { float x_ = (xx); \
    unsigned d_ = __float_as_uint(x_) - LOBITS; \
    cHigh += (x_ >= HI_F) ? 1u : 0u; \
    sHigh += (x_ >= HI_F) ? x_ : 0.f; \
    ms[(cntT < SLOTS) ? cntT : SLOTS] = x_; \
    cntT  += (d_ < WRANGE) ? 1u : 0u; }

    #pragma unroll 2
    for (int k = 0; k < COLS / 16 / THREADS; ++k) {      /* 8 iters, 4 float4 each */
        const int b = 4 * (tid + k * THREADS);
        float4 v0 = x4[b];
        float4 v1 = x4[b + 1];
        float4 v2 = x4[b + 2];
        float4 v3 = x4[b + 3];
        PROC(v0.x) PROC(v0.y) PROC(v0.z) PROC(v0.w)
        PROC(v1.x) PROC(v1.y) PROC(v1.z) PROC(v1.w)
        PROC(v2.x) PROC(v2.y) PROC(v2.z) PROC(v2.w)
        PROC(v3.x) PROC(v3.y) PROC(v3.z) PROC(v3.w)
    }
#undef PROC

    const unsigned myN  = (cntT < SLOTS) ? cntT : SLOTS;
    const unsigned cLow = (unsigned)EPT - cntT - cHigh;
    {
        unsigned a = wredU(cLow), b = wredU(cntT), mx = wredMaxU(cntT);
        float    s = wredF(sHigh);
        if (lane == 0) { rU1[wid] = a; rU2[wid] = b; rU3[wid] = mx; rF1[wid] = s; }
    }
    __syncthreads();
    if (tid == 0) {
        unsigned CL = 0u, CT = 0u, MX = 0u; float SH = 0.f;
        for (int w = 0; w < 8; ++w) {
            CL += rU1[w]; CT += rU2[w]; MX = (rU3[w] > MX) ? rU3[w] : MX;
            SH += rF1[w];
        }
        cntLowSh = CL; cHighSh = (unsigned)COLS - CL - CT; sHighSh = SH;
        if (MX > SLOTS || CL > K_RANK || CL + CT < K_RANK + 2u) fail = 1;
        rSh = K_RANK - CL;
    }
    __syncthreads();

    /* ---------- phase 2: exact select of rank r among captured ---------- */
    if (!fail) {
        if (tid < 64) hist[tid] = 0u;
        __syncthreads();
        for (unsigned j = 0; j < myN; ++j) {
            unsigned d = __float_as_uint(ms[j]) - LOBITS;
            atomicAdd(&hist[d >> 16], 1u);
        }
        __syncthreads();
        const unsigned r = rSh;
        if (wid == 0) {
            unsigned v = hist[lane], incl = v;
            #pragma unroll
            for (int o = 1; o < 64; o <<= 1) { unsigned n = __shfl_up(incl, o); if (lane >= o) incl += n; }
            unsigned excl = incl - v;
            if (v && excl <= r && r < incl) { selBin = lane; selBase = excl; }
        }
        __syncthreads();
        const int B = selBin;
        const unsigned j1 = r - selBase;
        if (tid < 64) hist[tid] = 0u;
        __syncthreads();
        for (unsigned j = 0; j < myN; ++j) {
            unsigned d = __float_as_uint(ms[j]) - LOBITS;
            if ((int)(d >> 16) == B) atomicAdd(&hist[(d >> 10) & 63u], 1u);
        }
        __syncthreads();
        if (wid == 0) {
            unsigned v = hist[lane], incl = v;
            #pragma unroll
            for (int o = 1; o < 64; o <<= 1) { unsigned n = __shfl_up(incl, o); if (lane >= o) incl += n; }
            unsigned excl = incl - v;
            if (v && excl <= j1 && j1 < incl) { fBin = lane; fBase = excl; }
        }
        __syncthreads();
        const int F = fBin;
        const unsigned j2 = j1 - fBase;
        for (unsigned j = 0; j < myN; ++j) {
            unsigned d = __float_as_uint(ms[j]) - LOBITS;
            if ((int)(d >> 16) == B && (int)((d >> 10) & 63u) == F) {
                unsigned idx = atomicAdd(&nCand, 1u);
                if (idx < 128u) cand[idx] = ms[j];
            }
        }
        __syncthreads();
        if (tid == 0 && nCand > 128u) fail = 1;
        __syncthreads();
        if (!fail) {
            unsigned nC = nCand;
            if (tid < (int)nC) {
                float v = cand[tid];
                unsigned lt = 0u, eq = 0u;
                for (unsigned i = 0; i < nC; ++i) {
                    float c = cand[i];
                    lt += (c < v) ? 1u : 0u;
                    eq += (c == v) ? 1u : 0u;
                }
                if (lt <= j2 && j2 < lt + eq) vrSh = v;
            }
        }
        __syncthreads();
        if (!fail) {
            /* s[K+1]: count <=vr (tie-run test) and min of capture above vr */
            const float vr = vrSh;
            unsigned le = 0u; float m1 = BIGF;
            for (unsigned j = 0; j < myN; ++j) {
                float x = ms[j];
                le += (x <= vr) ? 1u : 0u;
                if (x > vr) m1 = fminf(m1, x);
            }
            le = wredU(le); m1 = wredMinF(m1);
            if (lane == 0) { rU1[wid] = le; rF1[wid] = m1; }
            __syncthreads();
            if (tid == 0) {
                unsigned LE = cntLowSh; float M1 = BIGF;
                for (int w = 0; w < 8; ++w) { LE += rU1[w]; M1 = fminf(M1, rF1[w]); }
                float vr0 = vrSh;
                float v1  = (LE >= K_RANK + 2u) ? vr0 : M1;   /* tie-run -> s[K+1]==s[K] */
                if (v1 >= BIGF) fail = 1;                     /* s[K+1] not in window -> fallback */
                tSh = vr0 + 0.5f * (v1 - vr0);                /* t < HI <= every high value */
            }
            __syncthreads();
        }
    }
    __syncthreads();

    if (!fail) {
        /* ---------- phase 3: mean over {x > t} = window-part + high-part ---------- */
        const float t = tSh;
        float s = 0.f; unsigned c = 0u;
        for (unsigned j = 0; j < myN; ++j) {
            float x = ms[j];
            if (x > t) { s += x; c += 1u; }
        }
        s = wredF(s); c = wredU(c);
        if (lane == 0) { rF1[wid] = s; rU1[wid] = c; }
        __syncthreads();
        if (tid == 0) {
            float S = sHighSh; unsigned C = cHighSh;
            for (int w = 0; w < 8; ++w) { S += rF1[w]; C += rU1[w]; }
            out[row] = S / (float)((C > 0u) ? C : 1u);
        }
    } else {
        /* ---------- fallback: exact bisection on monotone keys (full re-read) ---------- */
        if (tid == 0) { loS = 0u; hiS = 0xFFFFFFFFu; }
        __syncthreads();
        for (int it = 0; it < 32; ++it) {
            unsigned mid = loS + ((hiS - loS) >> 1);
            unsigned c = 0u;
            for (int i = tid; i < COLS / 4; i += THREADS) {
                float4 v = x4[i];
                c += (key_of(v.x) <= mid) ? 1u : 0u;
                c += (key_of(v.y) <= mid) ? 1u : 0u;
                c += (key_of(v.z) <= mid) ? 1u : 0u;
                c += (key_of(v.w) <= mid) ? 1u : 0u;
            }
            c = wredU(c);
            if (lane == 0) rU1[wid] = c;
            __syncthreads();
            if (tid == 0) {
                unsigned t = 0u;
                for (int w = 0; w < 8; ++w) t += rU1[w];
                if (t >= K_RANK + 1u) hiS = mid; else loS = mid + 1u;
            }
            __syncthreads();
        }
        {
            const unsigned kap = loS;
            unsigned c = 0u, mA = 0xFFFFFFFFu;
            for (int i = tid; i < COLS / 4; i += THREADS) {
                float4 v = x4[i];
                float vv[4] = { v.x, v.y, v.z, v.w };
                #pragma unroll
                for (int cc = 0; cc < 4; ++cc) {
                    unsigned u = key_of(vv[cc]);
                    if (u <= kap) c += 1u; else mA = (u < mA) ? u : mA;
                }
            }
            c = wredU(c); mA = wredMinU(mA);
            if (lane == 0) { rU1[wid] = c; rU2[wid] = mA; }
            __syncthreads();
            if (tid == 0) {
                unsigned tot = 0u, m = 0xFFFFFFFFu;
                for (int w = 0; w < 8; ++w) { tot += rU1[w]; m = (rU2[w] < m) ? rU2[w] : m; }
                float vk  = float_of_key(kap);
                float vk1 = (tot >= K_RANK + 2u) ? vk : float_of_key(m);
                tSh = vk + 0.5f * (vk1 - vk);
            }
            __syncthreads();
        }
        {
            const float t = tSh;
            float s = 0.f; unsigned c = 0u;
            for (int i = tid; i < COLS / 4; i += THREADS) {
                float4 v = x4[i];
                if (v.x > t) { s += v.x; c += 1u; }
                if (v.y > t) { s += v.y; c += 1u; }
                if (v.z > t) { s += v.z; c += 1u; }
                if (v.w > t) { s += v.w; c += 1u; }
            }
            s = wredF(s); c = wredU(c);
            if (lane == 0) { rF1[wid] = s; rU1[wid] = c; }
            __syncthreads();
            if (tid == 0) {
                float S = 0.f; unsigned C = 0u;
                for (int w = 0; w < 8; ++w) { S += rF1[w]; C += rU1[w]; }
                out[row] = S / (float)((C > 0u) ? C : 1u);
            }
        }
    }
}

extern "C" void kernel_launch(void* const* d_in, const int* in_sizes, int n_in,
                              void* d_out, int out_size, void* d_ws, size_t ws_size,
                              hipStream_t stream) {
    const float* X = (const float*)d_in[0];
    float* out = (float*)d_out;
    const int rows = in_sizes[0] / COLS;   /* 512 */
    dtp_kernel<<<rows, THREADS, 0, stream>>>(X, out);
}

// Round 10
// 31.524 us; speedup vs baseline: 1.1986x; 1.0025x over previous
//
#include <hip/hip_runtime.h>

#define COLS    65536
#define THREADS 512
#define K_RANK  58981u          /* floor(0.9*(COLS-1)); frac = 0.5 */
#define SLOTS   12u
#define SSTRIDE 13              /* 12 data slots + 1 sacrificial; gcd(13,32)=1 */
#define LO_F    1.25f
#define HI_F    1.325f
#define BIGF    3.0e38f
#define EPT     (COLS / THREADS)   /* 128 elements per thread */

__device__ __forceinline__ unsigned key_of(float x) {
    unsigned b = __float_as_uint(x);
    return (b & 0x80000000u) ? ~b : (b | 0x80000000u);
}
__device__ __forceinline__ float float_of_key(unsigned u) {
    unsigned b = (u & 0x80000000u) ? (u & 0x7FFFFFFFu) : ~u;
    return __uint_as_float(b);
}
__device__ __forceinline__ float wredF(float v) {
    #pragma unroll
    for (int o = 32; o > 0; o >>= 1) v += __shfl_down(v, o);
    return v;
}
__device__ __forceinline__ unsigned wredU(unsigned v) {
    #pragma unroll
    for (int o = 32; o > 0; o >>= 1) v += __shfl_down(v, o);
    return v;
}
__device__ __forceinline__ unsigned wredMaxU(unsigned v) {
    #pragma unroll
    for (int o = 32; o > 0; o >>= 1) { unsigned n = __shfl_down(v, o); v = (n > v) ? n : v; }
    return v;
}
__device__ __forceinline__ unsigned wredMinU(unsigned v) {
    #pragma unroll
    for (int o = 32; o > 0; o >>= 1) { unsigned n = __shfl_down(v, o); v = (n < v) ? n : v; }
    return v;
}
__device__ __forceinline__ float wredMinF(float v) {
    #pragma unroll
    for (int o = 32; o > 0; o >>= 1) v = fminf(v, __shfl_down(v, o));
    return v;
}

__global__ __launch_bounds__(THREADS, 8)   /* 8 waves/EU -> 4 blocks/CU, VGPR<=64 */
void dtp_kernel(const float* __restrict__ X, float* __restrict__ out) {
    /* XCD-bijective row swizzle: 512 = 8 XCD * 64 */
    const int bid  = blockIdx.x;
    const int row  = (bid & 7) * 64 + (bid >> 3);
    const int tid  = threadIdx.x;
    const int lane = tid & 63;
    const int wid  = tid >> 6;
    const float4* x4 = (const float4*)(X + (size_t)row * COLS);

    __shared__ float    slot[THREADS * SSTRIDE];   /* 26624 B */
    __shared__ float    cand[128];
    __shared__ unsigned hist[64];
    __shared__ unsigned rU1[8], rU2[8], rU3[8];
    __shared__ float    rF1[8];
    __shared__ unsigned cntLowSh, cHighSh, nCand, rSh;
    __shared__ float    sHighSh, vrSh, tSh;
    __shared__ int      fail, selBin, fBin;
    __shared__ unsigned selBase, fBase;
    __shared__ unsigned loS, hiS;

    if (tid == 0) { fail = 0; nCand = 0u; }
    __syncthreads();

    const unsigned LOBITS = __float_as_uint(LO_F);
    const unsigned WRANGE = __float_as_uint(HI_F) - LOBITS;
    float* ms = &slot[tid * SSTRIDE];

    /* ---------- phase 1: branch-free stream, 64 B/lane (4x float4) ---------- */
    unsigned cntT = 0u, cHigh = 0u;
    float    sHigh = 0.f;

#define PROC(xx) { float x_ = (xx); \
    unsigned d_ = __float_as_uint(x_) - LOBITS; \
    cHigh += (x_ >= HI_F) ? 1u : 0u; \
    sHigh += (x_ >= HI_F) ? x_ : 0.f; \
    ms[(cntT < SLOTS) ? cntT : SLOTS] = x_; \
    cntT  += (d_ < WRANGE) ? 1u : 0u; }

    #pragma unroll 2
    for (int k = 0; k < COLS / 16 / THREADS; ++k) {      /* 8 iters, 4 float4 each */
        const int b = 4 * (tid + k * THREADS);
        float4 v0 = x4[b];
        float4 v1 = x4[b + 1];
        float4 v2 = x4[b + 2];
        float4 v3 = x4[b + 3];
        PROC(v0.x) PROC(v0.y) PROC(v0.z) PROC(v0.w)
        PROC(v1.x) PROC(v1.y) PROC(v1.z) PROC(v1.w)
        PROC(v2.x) PROC(v2.y) PROC(v2.z) PROC(v2.w)
        PROC(v3.x) PROC(v3.y) PROC(v3.z) PROC(v3.w)
    }
#undef PROC

    const unsigned myN  = (cntT < SLOTS) ? cntT : SLOTS;
    const unsigned cLow = (unsigned)EPT - cntT - cHigh;
    {
        unsigned a = wredU(cLow), b = wredU(cntT), mx = wredMaxU(cntT);
        float    s = wredF(sHigh);
        if (lane == 0) { rU1[wid] = a; rU2[wid] = b; rU3[wid] = mx; rF1[wid] = s; }
    }
    __syncthreads();
    if (tid == 0) {
        unsigned CL = 0u, CT = 0u, MX = 0u; float SH = 0.f;
        for (int w = 0; w < 8; ++w) {
            CL += rU1[w]; CT += rU2[w]; MX = (rU3[w] > MX) ? rU3[w] : MX;
            SH += rF1[w];
        }
        cntLowSh = CL; cHighSh = (unsigned)COLS - CL - CT; sHighSh = SH;
        if (MX > SLOTS || CL > K_RANK || CL + CT < K_RANK + 2u) fail = 1;
        rSh = K_RANK - CL;
    }
    __syncthreads();

    /* ---------- phase 2: exact select of rank r among captured ---------- */
    if (!fail) {
        if (tid < 64) hist[tid] = 0u;
        __syncthreads();
        for (unsigned j = 0; j < myN; ++j) {
            unsigned d = __float_as_uint(ms[j]) - LOBITS;
            atomicAdd(&hist[d >> 16], 1u);
        }
        __syncthreads();
        const unsigned r = rSh;
        if (wid == 0) {
            unsigned v = hist[lane], incl = v;
            #pragma unroll
            for (int o = 1; o < 64; o <<= 1) { unsigned n = __shfl_up(incl, o); if (lane >= o) incl += n; }
            unsigned excl = incl - v;
            if (v && excl <= r && r < incl) { selBin = lane; selBase = excl; }
        }
        __syncthreads();
        const int B = selBin;
        const unsigned j1 = r - selBase;
        if (tid < 64) hist[tid] = 0u;
        __syncthreads();
        for (unsigned j = 0; j < myN; ++j) {
            unsigned d = __float_as_uint(ms[j]) - LOBITS;
            if ((int)(d >> 16) == B) atomicAdd(&hist[(d >> 10) & 63u], 1u);
        }
        __syncthreads();
        if (wid == 0) {
            unsigned v = hist[lane], incl = v;
            #pragma unroll
            for (int o = 1; o < 64; o <<= 1) { unsigned n = __shfl_up(incl, o); if (lane >= o) incl += n; }
            unsigned excl = incl - v;
            if (v && excl <= j1 && j1 < incl) { fBin = lane; fBase = excl; }
        }
        __syncthreads();
        const int F = fBin;
        const unsigned j2 = j1 - fBase;
        for (unsigned j = 0; j < myN; ++j) {
            unsigned d = __float_as_uint(ms[j]) - LOBITS;
            if ((int)(d >> 16) == B && (int)((d >> 10) & 63u) == F) {
                unsigned idx = atomicAdd(&nCand, 1u);
                if (idx < 128u) cand[idx] = ms[j];
            }
        }
        __syncthreads();
        if (tid == 0 && nCand > 128u) fail = 1;
        __syncthreads();
        if (!fail) {
            unsigned nC = nCand;
            if (tid < (int)nC) {
                float v = cand[tid];
                unsigned lt = 0u, eq = 0u;
                for (unsigned i = 0; i < nC; ++i) {
                    float c = cand[i];
                    lt += (c < v) ? 1u : 0u;
                    eq += (c == v) ? 1u : 0u;
                }
                if (lt <= j2 && j2 < lt + eq) vrSh = v;
            }
        }
        __syncthreads();
        if (!fail) {
            /* s[K+1]: count <=vr (tie-run test) and min of capture above vr */
            const float vr = vrSh;
            unsigned le = 0u; float m1 = BIGF;
            for (unsigned j = 0; j < myN; ++j) {
                float x = ms[j];
                le += (x <= vr) ? 1u : 0u;
                if (x > vr) m1 = fminf(m1, x);
            }
            le = wredU(le); m1 = wredMinF(m1);
            if (lane == 0) { rU1[wid] = le; rF1[wid] = m1; }
            __syncthreads();
            if (tid == 0) {
                unsigned LE = cntLowSh; float M1 = BIGF;
                for (int w = 0; w < 8; ++w) { LE += rU1[w]; M1 = fminf(M1, rF1[w]); }
                float vr0 = vrSh;
                float v1  = (LE >= K_RANK + 2u) ? vr0 : M1;   /* tie-run -> s[K+1]==s[K] */
                if (v1 >= BIGF) fail = 1;                     /* s[K+1] not in window -> fallback */
                tSh = vr0 + 0.5f * (v1 - vr0);                /* t < HI <= every high value */
            }
            __syncthreads();
        }
    }
    __syncthreads();

    if (!fail) {
        /* ---------- phase 3: mean over {x > t} = window-part + high-part ---------- */
        const float t = tSh;
        float s = 0.f; unsigned c = 0u;
        for (unsigned j = 0; j < myN; ++j) {
            float x = ms[j];
            if (x > t) { s += x; c += 1u; }
        }
        s = wredF(s); c = wredU(c);
        if (lane == 0) { rF1[wid] = s; rU1[wid] = c; }
        __syncthreads();
        if (tid == 0) {
            float S = sHighSh; unsigned C = cHighSh;
            for (int w = 0; w < 8; ++w) { S += rF1[w]; C += rU1[w]; }
            out[row] = S / (float)((C > 0u) ? C : 1u);
        }
    } else {
        /* ---------- fallback: exact bisection on monotone keys (full re-read) ---------- */
        if (tid == 0) { loS = 0u; hiS = 0xFFFFFFFFu; }
        __syncthreads();
        for (int it = 0; it < 32; ++it) {
            unsigned mid = loS + ((hiS - loS) >> 1);
            unsigned c = 0u;
            for (int i = tid; i < COLS / 4; i += THREADS) {
                float4 v = x4[i];
                c += (key_of(v.x) <= mid) ? 1u : 0u;
                c += (key_of(v.y) <= mid) ? 1u : 0u;
                c += (key_of(v.z) <= mid) ? 1u : 0u;
                c += (key_of(v.w) <= mid) ? 1u : 0u;
            }
            c = wredU(c);
            if (lane == 0) rU1[wid] = c;
            __syncthreads();
            if (tid == 0) {
                unsigned t = 0u;
                for (int w = 0; w < 8; ++w) t += rU1[w];
                if (t >= K_RANK + 1u) hiS = mid; else loS = mid + 1u;
            }
            __syncthreads();
        }
        {
            const unsigned kap = loS;
            unsigned c = 0u, mA = 0xFFFFFFFFu;
            for (int i = tid; i < COLS / 4; i += THREADS) {
                float4 v = x4[i];
                float vv[4] = { v.x, v.y, v.z, v.w };
                #pragma unroll
                for (int cc = 0; cc < 4; ++cc) {
                    unsigned u = key_of(vv[cc]);
                    if (u <= kap) c += 1u; else mA = (u < mA) ? u : mA;
                }
            }
            c = wredU(c); mA = wredMinU(mA);
            if (lane == 0) { rU1[wid] = c; rU2[wid] = mA; }
            __syncthreads();
            if (tid == 0) {
                unsigned tot = 0u, m = 0xFFFFFFFFu;
                for (int w = 0; w < 8; ++w) { tot += rU1[w]; m = (rU2[w] < m) ? rU2[w] : m; }
                float vk  = float_of_key(kap);
                float vk1 = (tot >= K_RANK + 2u) ? vk : float_of_key(m);
                tSh = vk + 0.5f * (vk1 - vk);
            }
            __syncthreads();
        }
        {
            const float t = tSh;
            float s = 0.f; unsigned c = 0u;
            for (int i = tid; i < COLS / 4; i += THREADS) {
                float4 v = x4[i];
                if (v.x > t) { s += v.x; c += 1u; }
                if (v.y > t) { s += v.y; c += 1u; }
                if (v.z > t) { s += v.z; c += 1u; }
                if (v.w > t) { s += v.w; c += 1u; }
            }
            s = wredF(s); c = wredU(c);
            if (lane == 0) { rF1[wid] = s; rU1[wid] = c; }
            __syncthreads();
            if (tid == 0) {
                float S = 0.f; unsigned C = 0u;
                for (int w = 0; w < 8; ++w) { S += rF1[w]; C += rU1[w]; }
                out[row] = S / (float)((C > 0u) ? C : 1u);
            }
        }
    }
}

extern "C" void kernel_launch(void* const* d_in, const int* in_sizes, int n_in,
                              void* d_out, int out_size, void* d_ws, size_t ws_size,
                              hipStream_t stream) {
    const float* X = (const float*)d_in[0];
    float* out = (float*)d_out;
    const int rows = in_sizes[0] / COLS;   /* 512 */
    dtp_kernel<<<rows, THREADS, 0, stream>>>(X, out);
}